// Round 1
// baseline (460.387 us; speedup 1.0000x reference)
//
#include <hip/hip_runtime.h>
#include <stdint.h>

// Problem constants (fixed by reference): T=512, B=256, H=256, 3H=768.
// Strategy:
//   prep_weights: Wi,Wh (fp32 [256][768]) -> WiT,WhT (bf16 [768][256]) in ws.
//   gi_gemm:      GI[b][t][0:768] = bf16(ins[t][b]@Wi + bi)   (one big MFMA GEMM)
//   gru_scan:     reset-segment-parallel scan. 256 wgs (1/batch), 16 slots/wg,
//                 Wh held in registers as MFMA B-fragments (192 VGPR/lane).
// MFMA 16x16x32 bf16 layouts (HW-verified per guide):
//   A[m=lane&15][k=quad*8+j], B[k=quad*8+j][n=lane&15], C/D[row=quad*4+reg][col=lane&15]

typedef __attribute__((ext_vector_type(8))) __bf16 bf16x8;
typedef __attribute__((ext_vector_type(4))) float f32x4;

__device__ __forceinline__ float bf2f(unsigned short u) {
    union { unsigned int i; float f; } v; v.i = ((unsigned int)u) << 16; return v.f;
}
__device__ __forceinline__ unsigned short f2bf(float f) {
    union { float f; unsigned int i; } v; v.f = f;
    unsigned int x = v.i;
    x = x + 0x7fffu + ((x >> 16) & 1u);   // RNE
    return (unsigned short)(x >> 16);
}
__device__ __forceinline__ float fsig(float x) {
    return __builtin_amdgcn_rcpf(1.f + __builtin_amdgcn_exp2f(-1.442695041f * x));
}
__device__ __forceinline__ float ftanh(float x) {
    return 1.f - 2.f * __builtin_amdgcn_rcpf(1.f + __builtin_amdgcn_exp2f(2.885390082f * x));
}

// ---------------------------------------------------------------- prep
__global__ void prep_weights(const float* __restrict__ Wi, const float* __restrict__ Wh,
                             unsigned short* __restrict__ WiT, unsigned short* __restrict__ WhT) {
    const int idx = blockIdx.x * 256 + threadIdx.x;          // [0, 196608)
    const float* src = blockIdx.y ? Wh : Wi;
    unsigned short* dst = blockIdx.y ? WhT : WiT;
    const int c = idx >> 8, k = idx & 255;
    dst[c * 256 + k] = f2bf(src[k * 768 + c]);
}

// ---------------------------------------------------------------- kernel 1: GI = ins@Wi + bi
__launch_bounds__(512, 2)
__global__ void gi_gemm(const float* __restrict__ ins, const unsigned short* __restrict__ WiT,
                        const float* __restrict__ bi, unsigned short* __restrict__ GI) {
    __shared__ unsigned short a_buf[16 * 264];   // 16 rows x (256+8) bf16, stride 528 B
    __shared__ float gi_stage[16 * 776];         // 16 rows x (768+8) f32

    const int tid = threadIdx.x;
    const int lane = tid & 63, wv = tid >> 6;    // 8 waves
    const int quad = lane >> 4, n16 = lane & 15;

    // Wi B-fragments: wave owns hidden cols [32wv,32wv+32) of each gate (r,z,n)
    bf16x8 wfrag[3][2][8];
#pragma unroll
    for (int g = 0; g < 3; ++g)
#pragma unroll
        for (int tl = 0; tl < 2; ++tl) {
            const int c = g * 256 + wv * 32 + tl * 16 + n16;
            const unsigned short* src = WiT + c * 256 + quad * 8;
#pragma unroll
            for (int kt = 0; kt < 8; ++kt)
                wfrag[g][tl][kt] = *(const bf16x8*)(src + kt * 32);
        }
    float bi_r[3][2];
#pragma unroll
    for (int g = 0; g < 3; ++g)
#pragma unroll
        for (int tl = 0; tl < 2; ++tl)
            bi_r[g][tl] = bi[g * 256 + wv * 32 + tl * 16 + n16];

    const int srow = tid >> 5;        // staging row 0..15
    const int scol = (tid & 31) * 8;  // staging col

    float4 p0, p1;
    {
        const float* p = ins + (size_t)blockIdx.x * 16 * 256 + tid * 8;
        p0 = *(const float4*)p; p1 = *(const float4*)(p + 4);
    }

    for (int i = 0; i < 32; ++i) {
        const int chunk = blockIdx.x + i * 256;  // 16 consecutive rows of [T*B][256]
        // stage current chunk (prefetched) into LDS as bf16
        {
            bf16x8 av;
            av[0] = (__bf16)p0.x; av[1] = (__bf16)p0.y; av[2] = (__bf16)p0.z; av[3] = (__bf16)p0.w;
            av[4] = (__bf16)p1.x; av[5] = (__bf16)p1.y; av[6] = (__bf16)p1.z; av[7] = (__bf16)p1.w;
            *(bf16x8*)(&a_buf[srow * 264 + scol]) = av;
        }
        if (i + 1 < 32) {  // prefetch next chunk
            const float* p = ins + (size_t)(blockIdx.x + (i + 1) * 256) * 16 * 256 + tid * 8;
            p0 = *(const float4*)p; p1 = *(const float4*)(p + 4);
        }
        __syncthreads();

        f32x4 acc[3][2] = {};
#pragma unroll
        for (int kt = 0; kt < 8; ++kt) {
            bf16x8 af = *(const bf16x8*)(&a_buf[n16 * 264 + kt * 32 + quad * 8]);
#pragma unroll
            for (int g = 0; g < 3; ++g)
#pragma unroll
                for (int tl = 0; tl < 2; ++tl)
                    acc[g][tl] = __builtin_amdgcn_mfma_f32_16x16x32_bf16(af, wfrag[g][tl][kt], acc[g][tl], 0, 0, 0);
        }
        // epilogue: +bi, park in LDS (C-layout scatter), then coalesced bf16 store
#pragma unroll
        for (int g = 0; g < 3; ++g)
#pragma unroll
            for (int tl = 0; tl < 2; ++tl) {
                const int c = g * 256 + wv * 32 + tl * 16 + n16;
#pragma unroll
                for (int r = 0; r < 4; ++r)
                    gi_stage[(quad * 4 + r) * 776 + c] = acc[g][tl][r] + bi_r[g][tl];
            }
        __syncthreads();
        {
            const int r2 = tid >> 5;
            const int cb = (tid & 31) * 24;
            const int t = (chunk * 16) >> 8;
            const int b0 = (chunk * 16) & 255;
            unsigned short* dst = GI + ((size_t)(b0 + r2) * 512 + t) * 768 + cb;  // b-major GI
            const float* sp = &gi_stage[r2 * 776 + cb];
#pragma unroll
            for (int u = 0; u < 3; ++u) {
                bf16x8 o;
#pragma unroll
                for (int j = 0; j < 8; ++j) o[j] = (__bf16)sp[u * 8 + j];
                *(bf16x8*)(dst + u * 8) = o;
            }
        }
        // next stage write to a_buf is safe: all gemm reads completed before 2nd barrier
    }
}

// ---------------------------------------------------------------- kernel 2: segment-parallel GRU scan
__launch_bounds__(512, 2)
__global__ void gru_scan(const unsigned short* __restrict__ GI, const int* __restrict__ resets,
                         const float* __restrict__ carry, const unsigned short* __restrict__ WhT,
                         const float* __restrict__ bhn, float* __restrict__ out) {
    __shared__ int s_reset[512];
    __shared__ unsigned short s_h[2][16 * 264];    // h (bf16), A-operand staging, dbuf
    __shared__ unsigned short s_gi[2][16 * 784];   // gi rows for current slots, dbuf

    const int b = blockIdx.x;
    const int tid = threadIdx.x;
    const int lane = tid & 63, wv = tid >> 6;
    const int quad = lane >> 4, n16 = lane & 15;

    s_reset[tid] = resets[tid * 256 + b];

    // Wh B-fragments (held in VGPRs for the whole scan)
    bf16x8 wfrag[3][2][8];
#pragma unroll
    for (int g = 0; g < 3; ++g)
#pragma unroll
        for (int tl = 0; tl < 2; ++tl) {
            const int c = g * 256 + wv * 32 + tl * 16 + n16;
            const unsigned short* src = WhT + c * 256 + quad * 8;
#pragma unroll
            for (int kt = 0; kt < 8; ++kt)
                wfrag[g][tl][kt] = *(const bf16x8*)(src + kt * 32);
        }
    float bhn_r[2];
    bhn_r[0] = bhn[wv * 32 + n16];
    bhn_r[1] = bhn[wv * 32 + 16 + n16];

    __syncthreads();

    // slot state: slot = quad*4+r owns window [slot*32, slot*32+32); processes every
    // segment starting there to its full extent. t_s = next timestep (-1 = done).
    int t_s[4];
    float h_prev[2][4];
#pragma unroll
    for (int r = 0; r < 4; ++r) {
        const int slot = quad * 4 + r;
        const int w0 = slot * 32;
        int found = -1;
        for (int t = w0; t < w0 + 32; ++t) {
            if (t == 0 || s_reset[t] != 0) { found = t; break; }
        }
        t_s[r] = found;
        float h0 = 0.f, h1 = 0.f;
        if (found == 0 && s_reset[0] == 0) {  // faithful: initial carry (zeros in harness)
            h0 = carry[b * 256 + wv * 32 + n16];
            h1 = carry[b * 256 + wv * 32 + 16 + n16];
        }
        h_prev[0][r] = h0; h_prev[1][r] = h1;
        s_h[0][slot * 264 + wv * 32 + n16] = f2bf(h0);
        s_h[0][slot * 264 + wv * 32 + 16 + n16] = f2bf(h1);
    }

    int buf = 0;
    for (int it = 0; it < 513; ++it) {
        const bool any = (t_s[0] >= 0) | (t_s[1] >= 0) | (t_s[2] >= 0) | (t_s[3] >= 0);
        if (__ballot((int)any) == 0ull) break;   // every wave tracks all 16 slots -> uniform

        // stage gi rows for slots 2wv, 2wv+1 into s_gi[buf] (coalesced 1536B row / wave)
        {
            const int src_lane = (wv >> 1) * 16;  // a lane whose quad tracks these slots
            const int v0 = __builtin_amdgcn_readlane(t_s[0], src_lane);
            const int v1 = __builtin_amdgcn_readlane(t_s[1], src_lane);
            const int v2 = __builtin_amdgcn_readlane(t_s[2], src_lane);
            const int v3 = __builtin_amdgcn_readlane(t_s[3], src_lane);
            const int tr0 = (wv & 1) ? v2 : v0;
            const int tr1 = (wv & 1) ? v3 : v1;
            if (tr0 >= 0) {
                const unsigned short* src = GI + ((size_t)b * 512 + tr0) * 768 + lane * 12;
                unsigned short* d = &s_gi[buf][(2 * wv) * 784 + lane * 12];
                ((uint2*)d)[0] = ((const uint2*)src)[0];
                ((uint2*)d)[1] = ((const uint2*)src)[1];
                ((uint2*)d)[2] = ((const uint2*)src)[2];
            }
            if (tr1 >= 0) {
                const unsigned short* src = GI + ((size_t)b * 512 + tr1) * 768 + lane * 12;
                unsigned short* d = &s_gi[buf][(2 * wv + 1) * 784 + lane * 12];
                ((uint2*)d)[0] = ((const uint2*)src)[0];
                ((uint2*)d)[1] = ((const uint2*)src)[1];
                ((uint2*)d)[2] = ((const uint2*)src)[2];
            }
        }
        __syncthreads();  // single barrier per iteration (gi + h double-buffered)

        // gh = h @ Wh for all 16 slots
        f32x4 acc[3][2] = {};
#pragma unroll
        for (int kt = 0; kt < 8; ++kt) {
            bf16x8 af = *(const bf16x8*)(&s_h[buf][n16 * 264 + kt * 32 + quad * 8]);
#pragma unroll
            for (int g = 0; g < 3; ++g)
#pragma unroll
                for (int tl = 0; tl < 2; ++tl)
                    acc[g][tl] = __builtin_amdgcn_mfma_f32_16x16x32_bf16(af, wfrag[g][tl][kt], acc[g][tl], 0, 0, 0);
        }

        // gates + h update + state transition
#pragma unroll
        for (int r = 0; r < 4; ++r) {
            const int slot = quad * 4 + r;
            const int t_cur = t_s[r];
            const bool alive = t_cur >= 0;
            float hnew[2];
#pragma unroll
            for (int tl = 0; tl < 2; ++tl) {
                const int c = wv * 32 + tl * 16 + n16;
                const float gr = bf2f(s_gi[buf][slot * 784 + c]);
                const float gz = bf2f(s_gi[buf][slot * 784 + 256 + c]);
                const float gn = bf2f(s_gi[buf][slot * 784 + 512 + c]);
                const float rr = fsig(gr + acc[0][tl][r]);
                const float zz = fsig(gz + acc[1][tl][r]);
                const float nn = ftanh(gn + rr * (acc[2][tl][r] + bhn_r[tl]));
                hnew[tl] = (1.f - zz) * nn + zz * h_prev[tl][r];
                if (alive) out[((size_t)t_cur * 256 + b) * 256 + c] = hnew[tl];
            }
            // advance: stop at T or at a reset that belongs to a later window
            int tnext = -1;
            bool zero_h = true;  // dead slots keep h=0 (keeps LDS finite)
            if (alive) {
                const int tn = t_cur + 1;
                if (tn < 512) {
                    const bool rst = s_reset[tn] != 0;
                    if (!(rst && tn >= (slot + 1) * 32)) {
                        tnext = tn;
                        zero_h = rst;  // reset inside own window: new segment, h=0
                    }
                }
            }
            t_s[r] = tnext;
            const float k0 = zero_h ? 0.f : hnew[0];
            const float k1 = zero_h ? 0.f : hnew[1];
            h_prev[0][r] = k0; h_prev[1][r] = k1;
            s_h[buf ^ 1][slot * 264 + wv * 32 + n16] = f2bf(k0);
            s_h[buf ^ 1][slot * 264 + wv * 32 + 16 + n16] = f2bf(k1);
        }
        buf ^= 1;
    }
}

// ---------------------------------------------------------------- launch
extern "C" void kernel_launch(void* const* d_in, const int* in_sizes, int n_in,
                              void* d_out, int out_size, void* d_ws, size_t ws_size,
                              hipStream_t stream) {
    const float* ins   = (const float*)d_in[0];
    const int* resets  = (const int*)d_in[1];
    const float* carry = (const float*)d_in[2];
    const float* Wi    = (const float*)d_in[3];
    const float* bi    = (const float*)d_in[4];
    const float* Wh    = (const float*)d_in[5];
    const float* bhn   = (const float*)d_in[6];
    float* out = (float*)d_out;

    unsigned short* WiT = (unsigned short*)d_ws;        // [768][256] bf16
    unsigned short* WhT = WiT + 196608;                 // [768][256] bf16
    unsigned short* GI  = WhT + 196608;                 // [256][512][768] bf16 (b-major)

    prep_weights<<<dim3(768, 2), dim3(256), 0, stream>>>(Wi, Wh, WiT, WhT);
    gi_gemm<<<dim3(256), dim3(512), 0, stream>>>(ins, WiT, bi, GI);
    gru_scan<<<dim3(256), dim3(512), 0, stream>>>(GI, resets, carry, WhT, bhn, out);
}